// Round 5
// baseline (335.148 us; speedup 1.0000x reference)
//
#include <hip/hip_runtime.h>
#include <stdint.h>

// Problem constants
#define M_BATCH 32768
#define N_OUT   1024
#define K_IN    1024

// GEMM tile (round-2 proven geometry)
#define BM 128
#define BN 128
#define BK 64
#define NT (K_IN / BK)   // 16

typedef __attribute__((ext_vector_type(8))) short  short8;
typedef __attribute__((ext_vector_type(4))) float  f32x4;

__device__ __forceinline__ unsigned short f2bf(float f) {
    __bf16 h = (__bf16)f;
    return __builtin_bit_cast(unsigned short, h);
}

typedef const __attribute__((address_space(1))) unsigned int* gas_ptr;
typedef __attribute__((address_space(3))) unsigned int*       las_ptr;

__device__ __forceinline__ void gload_lds16(const void* g, void* l) {
    // async global->LDS, 16B/lane; LDS dest = wave-uniform base + lane*16
    __builtin_amdgcn_global_load_lds((gas_ptr)g, (las_ptr)l, 16, 0, 0);
}

// ---------------------------------------------------------------------------
// Kernel 1: materialize W (bf16) from eigens.
// W[y*8+j][xb*8+c] = eigens[y][xb][(j-c)&7]
// ---------------------------------------------------------------------------
__global__ __launch_bounds__(256) void build_w(const float* __restrict__ eig,
                                               unsigned short* __restrict__ W) {
    int tid = blockIdx.x * 256 + threadIdx.x;   // 0..16383
    int y  = tid >> 7;
    int xb = tid & 127;
    const float* e = eig + (size_t)((y << 7) + xb) * 8;
    f32x4 e0 = *reinterpret_cast<const f32x4*>(e);
    f32x4 e1 = *reinterpret_cast<const f32x4*>(e + 4);
    float ev[8] = {e0[0], e0[1], e0[2], e0[3], e1[0], e1[1], e1[2], e1[3]};
#pragma unroll
    for (int j = 0; j < 8; ++j) {
        alignas(16) unsigned short wv[8];
#pragma unroll
        for (int c = 0; c < 8; ++c) wv[c] = f2bf(ev[(j - c) & 7]);
        *reinterpret_cast<uint4*>(W + (size_t)(y * 8 + j) * K_IN + xb * 8) =
            *reinterpret_cast<const uint4*>(wv);
    }
}

// ---------------------------------------------------------------------------
// Kernel 2: fused GEMM. C[M,N] = cvt_bf16(A_f32)[M,K] * W[N,K]^T, fp32 out.
// Round-2 structure (128x128, BK=64, 4 waves 2x2, 16x16x32 MFMA, XOR-swizzled
// LDS) with:
//   - B staged via global_load_lds (round-2 verbatim, proven 0-conflict)
//   - A staged from f32 GLOBAL with one-tile-lookahead reg staging:
//       iter t: issue B(t) gloads;
//               cvt+ds_write A(t) (loads issued in iter t-1, latency hidden);
//               issue A(t+1) f32 loads (stay in flight across the barrier);
//               s_waitcnt vmcnt(8) (drains B(t) only) + lgkmcnt(0); s_barrier.
//   - A ds_write pattern/image = round-1 verbatim (measured 0 bank conflicts).
// Race-safety: single LDS buffer; entry barrier ensures all reads of tile t-1
// done before any write of tile t; second barrier (with vmcnt(8)+lgkmcnt(0))
// ensures B landed + A writes visible; A(t+1) loads write only registers.
// ---------------------------------------------------------------------------
__global__ __launch_bounds__(256) void gemm_fused(const float* __restrict__ A,
                                                  const unsigned short* __restrict__ W,
                                                  float* __restrict__ C) {
    __shared__ unsigned short Alds[BM * BK];    // 16 KiB
    __shared__ unsigned short Blds[BN * BK];    // 16 KiB

    // XCD-aware bijective swizzle (nwg=2048, %8==0): the 8 N-blocks of one
    // M-panel run consecutively on one XCD -> A panel (512KB f32) L2-hits.
    const int bid  = blockIdx.x;
    const int swz  = (bid & 7) * 256 + (bid >> 3);
    const int nblk = swz & 7;
    const int mblk = swz >> 3;
    const int brow = mblk * BM;
    const int bcol = nblk * BN;

    const int tid  = threadIdx.x;
    const int lane = tid & 63;
    const int wv   = tid >> 6;                   // wave 0..3
    const int wm   = wv >> 1;
    const int wn   = wv & 1;

    f32x4 acc[4][4];
    const f32x4 zero = {0.f, 0.f, 0.f, 0.f};
#pragma unroll
    for (int i = 0; i < 4; ++i)
#pragma unroll
        for (int j = 0; j < 4; ++j) acc[i][j] = zero;

    // ---- A staging map (round-1 verbatim, HW-measured conflict-free):
    // thread covers rows srow + it*32 (it=0..3), 16B LDS slot sslot; the
    // SOURCE k-chunk is pre-swizzled: sk8 = sslot ^ (row&7).
    const int srow  = tid >> 3;                  // 0..31
    const int sslot = tid & 7;
    const int sk8   = sslot ^ (srow & 7);
    const float*    Af    = A + (size_t)(brow + srow) * K_IN + sk8 * 8;
    unsigned short* AldsW = Alds + srow * BK + sslot * 8;

    // ---- B staging map (round-2 verbatim): wave wv stages 4 segments of 8
    // rows; lane l -> row l>>3, chunk (l&7)^(l>>3) (pre-swizzled source).
    const int lrow = lane >> 3;
    const int lchk = (lane & 7) ^ lrow;
    const unsigned short* Bbase = W + (size_t)(bcol + wv * 32 + lrow) * K_IN + lchk * 8;
    unsigned short* BldsBase = Blds + wv * 2048;

    // ---- prologue: issue A(0) f32 loads (land during iter 0's entry phase)
    f32x4 aPre[4][2];
#pragma unroll
    for (int it = 0; it < 4; ++it) {
        const float* s = Af + (size_t)it * 32 * K_IN;
        aPre[it][0] = *reinterpret_cast<const f32x4*>(s);
        aPre[it][1] = *reinterpret_cast<const f32x4*>(s + 4);
    }

    for (int t = 0; t < NT; ++t) {
        const int kt  = t * BK;
        const int ktn = (kt + BK) & (K_IN - 1);  // wraps to 0 on last iter (harmless)

        __builtin_amdgcn_s_barrier();            // entry: tile t-1 fully consumed
        __builtin_amdgcn_sched_barrier(0);

        // ---- issue B(t) global_load_lds (4 per wave)
#pragma unroll
        for (int s = 0; s < 4; ++s)
            gload_lds16(Bbase + (size_t)(s * 8) * K_IN + kt, BldsBase + s * 512);
        asm volatile("" ::: "memory");           // pin: B issued before A(t+1)

        // ---- cvt + ds_write A(t) (compiler inserts precise vmcnt for aPre)
#pragma unroll
        for (int it = 0; it < 4; ++it) {
            short8 b;
#pragma unroll
            for (int i = 0; i < 4; ++i) b[i]     = (short)f2bf(aPre[it][0][i]);
#pragma unroll
            for (int i = 0; i < 4; ++i) b[i + 4] = (short)f2bf(aPre[it][1][i]);
            *reinterpret_cast<short8*>(AldsW + it * 32 * BK) = b;
        }

        // ---- issue A(t+1) f32 loads into aPre (regs now dead after cvt);
        //      these stay IN FLIGHT across the barrier (counted vmcnt).
#pragma unroll
        for (int it = 0; it < 4; ++it) {
            const float* s = Af + (size_t)it * 32 * K_IN + ktn;
            aPre[it][0] = *reinterpret_cast<const f32x4*>(s);
            aPre[it][1] = *reinterpret_cast<const f32x4*>(s + 4);
        }

        // ---- drain B (oldest 4) + A ds_writes; keep 8 A(t+1) loads flying
        asm volatile("s_waitcnt vmcnt(8) lgkmcnt(0)" ::: "memory");
        __builtin_amdgcn_s_barrier();
        __builtin_amdgcn_sched_barrier(0);

        // ---- compute (round-2 verbatim): 2 k-substeps x (8 ds_read + 16 MFMA)
#pragma unroll
        for (int ks = 0; ks < 2; ++ks) {
            short8 af[4], bfr[4];
            const int cb = ks * 4 + (lane >> 4); // global 16B k-chunk 0..7
            const int sl = cb ^ (lane & 7);      // swizzled LDS slot
#pragma unroll
            for (int mt = 0; mt < 4; ++mt) {
                int row = wm * 64 + mt * 16 + (lane & 15);
                af[mt] = *reinterpret_cast<const short8*>(Alds + row * BK + sl * 8);
            }
#pragma unroll
            for (int nt = 0; nt < 4; ++nt) {
                int row = wn * 64 + nt * 16 + (lane & 15);
                bfr[nt] = *reinterpret_cast<const short8*>(Blds + row * BK + sl * 8);
            }
            __builtin_amdgcn_s_setprio(1);
#pragma unroll
            for (int mt = 0; mt < 4; ++mt)
#pragma unroll
                for (int nt = 0; nt < 4; ++nt)
                    acc[mt][nt] = __builtin_amdgcn_mfma_f32_16x16x32_bf16(
                        af[mt], bfr[nt], acc[mt][nt], 0, 0, 0);
            __builtin_amdgcn_s_setprio(0);
        }
    }

    // ---- epilogue: C/D layout col = lane&15, row = (lane>>4)*4 + reg
#pragma unroll
    for (int mt = 0; mt < 4; ++mt) {
#pragma unroll
        for (int nt = 0; nt < 4; ++nt) {
            int col = bcol + wn * 64 + nt * 16 + (lane & 15);
#pragma unroll
            for (int r = 0; r < 4; ++r) {
                int row = brow + wm * 64 + mt * 16 + (lane >> 4) * 4 + r;
                C[(size_t)row * N_OUT + col] = acc[mt][nt][r];
            }
        }
    }
}

extern "C" void kernel_launch(void* const* d_in, const int* in_sizes, int n_in,
                              void* d_out, int out_size, void* d_ws, size_t ws_size,
                              hipStream_t stream) {
    const float* x   = (const float*)d_in[0];    // [32768,1024] f32
    const float* eig = (const float*)d_in[1];    // [128,128,8]  f32
    float* out = (float*)d_out;                  // [32768,1024] f32

    const size_t W_ELTS = (size_t)N_OUT * K_IN;  // 2 MiB bf16 scratch
    if (ws_size < W_ELTS * sizeof(unsigned short)) return;
    unsigned short* W = (unsigned short*)d_ws;

    hipLaunchKernelGGL(build_w, dim3(64), dim3(256), 0, stream, eig, W);
    hipLaunchKernelGGL(gemm_fused, dim3((M_BATCH / BM) * (N_OUT / BN)), dim3(256),
                       0, stream, x, W, out);
}